// Round 4
// baseline (328.941 us; speedup 1.0000x reference)
//
#include <hip/hip_runtime.h>

#define N_NODES 10000
#define N_EDGES 320000
#define DIN 512
#define DHID 512
#define DOUT 256

typedef __bf16 bf16x8 __attribute__((ext_vector_type(8)));
typedef float f32x4 __attribute__((ext_vector_type(4)));
typedef unsigned short ushort_t;
typedef unsigned int uint_t;

__device__ __forceinline__ float b2f(ushort_t u){
    union { uint_t i; float f; } v; v.i = (uint_t)u << 16; return v.f;
}
__device__ __forceinline__ ushort_t f2b(float f){
    union { float f; uint_t i; } v; v.f = f;
    uint_t i = v.i;
    return (ushort_t)((i + 0x7fffu + ((i >> 16) & 1u)) >> 16); // RNE
}

__device__ __forceinline__ void gll16(const ushort_t* g, ushort_t* l){
    __builtin_amdgcn_global_load_lds(
        (const __attribute__((address_space(1))) unsigned int*)g,
        (__attribute__((address_space(3))) unsigned int*)l,
        16, 0, 0);
}

// ---------------- CSR build ----------------

__global__ void k_degree(const int* __restrict__ dst, int* __restrict__ deg){
    int e = blockIdx.x * 256 + threadIdx.x;
    if (e < N_EDGES) atomicAdd(&deg[dst[e]], 1);
}

__global__ void k_scan(const int* __restrict__ deg, int* __restrict__ row_ptr,
                       int* __restrict__ cursor){
    __shared__ int buf[1024];
    __shared__ int carry;
    int t = threadIdx.x;
    if (t == 0){ carry = 0; row_ptr[0] = 0; }
    __syncthreads();
    for (int c = 0; c < 10; ++c){
        int idx = c * 1024 + t;
        int v = (idx < N_NODES) ? deg[idx] : 0;
        buf[t] = v;
        __syncthreads();
        for (int off = 1; off < 1024; off <<= 1){
            int x = (t >= off) ? buf[t - off] : 0;
            __syncthreads();
            buf[t] += x;
            __syncthreads();
        }
        int inc = buf[t] + carry;   // inclusive prefix + carry
        if (idx < N_NODES){
            row_ptr[idx + 1] = inc;
            cursor[idx] = inc - v;  // exclusive prefix = bucket start
        }
        __syncthreads();
        if (t == 1023) carry = inc;
        __syncthreads();
    }
}

__global__ void k_scatter(const int* __restrict__ src, const int* __restrict__ dst,
                          int* __restrict__ cursor, int* __restrict__ srcs){
    int e = blockIdx.x * 256 + threadIdx.x;
    if (e < N_EDGES){
        int p = atomicAdd(&cursor[dst[e]], 1);
        srcs[p] = src[e];
    }
}

// ---------------- weight f32 -> bf16 conversion (once per call) ----------------

struct CvtArgs { const float* s[9]; ushort_t* d[9]; int n[9]; };

__global__ void k_cvt(CvtArgs a){
    int m = blockIdx.y;
    int i = (blockIdx.x * 256 + threadIdx.x) * 8;
    if (i < a.n[m]){
        const float* sp = a.s[m] + i;
        float4 f0 = *(const float4*)sp;
        float4 f1 = *(const float4*)(sp + 4);
        uint4 u;
        u.x = (uint_t)f2b(f0.x) | ((uint_t)f2b(f0.y) << 16);
        u.y = (uint_t)f2b(f0.z) | ((uint_t)f2b(f0.w) << 16);
        u.z = (uint_t)f2b(f1.x) | ((uint_t)f2b(f1.y) << 16);
        u.w = (uint_t)f2b(f1.z) | ((uint_t)f2b(f1.w) << 16);
        *(uint4*)&a.d[m][i] = u;
    }
}

// ---------------- pe = w_pe^T + b_pe (LDS tile transpose, f32 -> bf16) ----------------

__global__ void k_pe(const float* __restrict__ w_pe, const float* __restrict__ b_pe,
                     ushort_t* __restrict__ h0){
    __shared__ float lt[64][68];  // [n_local][i_local], padded
    int t = threadIdx.x;
    int n0 = blockIdx.x * 64, i0 = blockIdx.y * 64;
    int nc = (t & 15) * 4, ir = t >> 4;   // ir 0..15
    #pragma unroll
    for (int p = 0; p < 4; ++p){
        int i_loc = ir + p * 16;
        float4 v = {0.f, 0.f, 0.f, 0.f};
        if (n0 + nc < N_NODES)  // N_NODES % 4 == 0, chunk-level guard OK
            v = *(const float4*)&w_pe[(size_t)(i0 + i_loc) * N_NODES + n0 + nc];
        lt[nc + 0][i_loc] = v.x;
        lt[nc + 1][i_loc] = v.y;
        lt[nc + 2][i_loc] = v.z;
        lt[nc + 3][i_loc] = v.w;
    }
    __syncthreads();
    int ic = t & 7, nr = t >> 3;   // nr 0..31
    #pragma unroll
    for (int p = 0; p < 2; ++p){
        int n_loc = nr + p * 32;
        int n = n0 + n_loc;
        if (n < N_NODES){
            uint4 u;
            uint_t w01 = (uint_t)f2b(lt[n_loc][ic*8+0] + b_pe[i0+ic*8+0])
                       | ((uint_t)f2b(lt[n_loc][ic*8+1] + b_pe[i0+ic*8+1]) << 16);
            uint_t w23 = (uint_t)f2b(lt[n_loc][ic*8+2] + b_pe[i0+ic*8+2])
                       | ((uint_t)f2b(lt[n_loc][ic*8+3] + b_pe[i0+ic*8+3]) << 16);
            uint_t w45 = (uint_t)f2b(lt[n_loc][ic*8+4] + b_pe[i0+ic*8+4])
                       | ((uint_t)f2b(lt[n_loc][ic*8+5] + b_pe[i0+ic*8+5]) << 16);
            uint_t w67 = (uint_t)f2b(lt[n_loc][ic*8+6] + b_pe[i0+ic*8+6])
                       | ((uint_t)f2b(lt[n_loc][ic*8+7] + b_pe[i0+ic*8+7]) << 16);
            u.x = w01; u.y = w23; u.z = w45; u.w = w67;
            *(uint4*)&h0[(size_t)n * DIN + i0 + ic * 8] = u;
        }
    }
}

// ---------------- mean aggregation, panel-split for per-XCD L2 residency ----------------

__global__ __launch_bounds__(256) void k_agg(
    const ushort_t* __restrict__ X, const int* __restrict__ row_ptr,
    const int* __restrict__ srcs, ushort_t* __restrict__ out)
{
    int w = threadIdx.x >> 6, lane = threadIdx.x & 63;
    int n = blockIdx.x * 4 + w;
    int col = blockIdx.y * 128 + lane * 2;
    int beg = row_ptr[n], end = row_ptr[n + 1];
    float a0 = 0.f, a1 = 0.f;
    int j = beg;
    for (; j + 4 <= end; j += 4){
        int s0 = srcs[j + 0], s1 = srcs[j + 1], s2 = srcs[j + 2], s3 = srcs[j + 3];
        uint_t v0 = *(const uint_t*)&X[(size_t)s0 * 512 + col];
        uint_t v1 = *(const uint_t*)&X[(size_t)s1 * 512 + col];
        uint_t v2 = *(const uint_t*)&X[(size_t)s2 * 512 + col];
        uint_t v3 = *(const uint_t*)&X[(size_t)s3 * 512 + col];
        a0 += b2f((ushort_t)(v0 & 0xffffu)); a1 += b2f((ushort_t)(v0 >> 16));
        a0 += b2f((ushort_t)(v1 & 0xffffu)); a1 += b2f((ushort_t)(v1 >> 16));
        a0 += b2f((ushort_t)(v2 & 0xffffu)); a1 += b2f((ushort_t)(v2 >> 16));
        a0 += b2f((ushort_t)(v3 & 0xffffu)); a1 += b2f((ushort_t)(v3 >> 16));
    }
    for (; j < end; ++j){
        int s = srcs[j];
        uint_t v = *(const uint_t*)&X[(size_t)s * 512 + col];
        a0 += b2f((ushort_t)(v & 0xffffu)); a1 += b2f((ushort_t)(v >> 16));
    }
    float inv = (end > beg) ? 1.f / (float)(end - beg) : 1.f;
    uint_t o = (uint_t)f2b(a0 * inv) | ((uint_t)f2b(a1 * inv) << 16);
    *(uint_t*)&out[(size_t)n * 512 + col] = o;
}

// ---------------- fused SAGE layer, m97-structure ----------------
// BM=128, BN=64, BK=32; 4 waves (2x2), wave tile 64x32; global_load_lds 16B staging.
// Y(f32) = [leaky?](X@Ws^T + Agg@Wn^T + b) + X@Wr^T + rb

template<int DO, bool ACT, bool DUAL2, bool WRITE_BF>
__global__ __launch_bounds__(256) void k_layer(
    const ushort_t* __restrict__ X, const ushort_t* __restrict__ G,
    const ushort_t* __restrict__ Ws, const ushort_t* __restrict__ Wn,
    const ushort_t* __restrict__ Wr,
    const float* __restrict__ b, const float* __restrict__ rb,
    float* __restrict__ Y, float* __restrict__ Y2, ushort_t* __restrict__ YB)
{
    __shared__ __align__(16) ushort_t sX[128][32];   // 8KB, rows 64B, linear
    __shared__ __align__(16) ushort_t sG[128][32];   // 8KB
    __shared__ __align__(16) ushort_t sWs[64][32];   // 4KB
    __shared__ __align__(16) ushort_t sWn[64][32];   // 4KB
    __shared__ __align__(16) ushort_t sWr[64][32];   // 4KB

    int t = threadIdx.x;
    int m0 = blockIdx.x * 128, n0 = blockIdx.y * 64;
    int lane = t & 63, w = t >> 6;
    int wr = w >> 1, wc = w & 1;           // wave tile: rows wr*64, cols wc*32

    // per-wave staging chunk setup: 28 chunks of 1KB (16 rows x 64B), 7 per wave
    const ushort_t* gptr[7];
    ushort_t* lptr[7];
    int rl = lane >> 2, sl = (lane & 3) * 8;
    #pragma unroll
    for (int i = 0; i < 7; ++i){
        int q = w * 7 + i;
        const ushort_t* gA; int rowbase; ushort_t* lb;
        if (q < 8)       { gA = X;  rowbase = m0 + q * 16;        lb = &sX[q * 16][0]; }
        else if (q < 16) { gA = G;  rowbase = m0 + (q - 8) * 16;  lb = &sG[(q - 8) * 16][0]; }
        else if (q < 20) { gA = Ws; rowbase = n0 + (q - 16) * 16; lb = &sWs[(q - 16) * 16][0]; }
        else if (q < 24) { gA = Wn; rowbase = n0 + (q - 20) * 16; lb = &sWn[(q - 20) * 16][0]; }
        else             { gA = Wr; rowbase = n0 + (q - 24) * 16; lb = &sWr[(q - 24) * 16][0]; }
        gptr[i] = gA + (size_t)(rowbase + rl) * 512 + sl;
        lptr[i] = lb;   // wave-uniform; HW writes base + lane*16
    }

    f32x4 accS[4][2] = {}, accG[4][2] = {}, accR[4][2] = {};
    int arow = wr * 64 + (lane & 15);
    int brow = wc * 32 + (lane & 15);
    int kk = (lane >> 4) * 8;

    for (int k0 = 0; k0 < 512; k0 += 32){
        __syncthreads();   // prior compute done before overwrite
        #pragma unroll
        for (int i = 0; i < 7; ++i) gll16(gptr[i] + k0, lptr[i]);
        __syncthreads();   // compiler drains vmcnt before barrier

        bf16x8 ax[4], ag[4], bs[2], bn_[2], brr[2];
        #pragma unroll
        for (int m = 0; m < 4; ++m){
            ax[m] = *(const bf16x8*)&sX[arow + m * 16][kk];
            ag[m] = *(const bf16x8*)&sG[arow + m * 16][kk];
        }
        #pragma unroll
        for (int n = 0; n < 2; ++n){
            bs[n]  = *(const bf16x8*)&sWs[brow + n * 16][kk];
            bn_[n] = *(const bf16x8*)&sWn[brow + n * 16][kk];
            brr[n] = *(const bf16x8*)&sWr[brow + n * 16][kk];
        }
        #pragma unroll
        for (int m = 0; m < 4; ++m)
            #pragma unroll
            for (int n = 0; n < 2; ++n){
                accS[m][n] = __builtin_amdgcn_mfma_f32_16x16x32_bf16(ax[m], bs[n],  accS[m][n], 0, 0, 0);
                accG[m][n] = __builtin_amdgcn_mfma_f32_16x16x32_bf16(ag[m], bn_[n], accG[m][n], 0, 0, 0);
                accR[m][n] = __builtin_amdgcn_mfma_f32_16x16x32_bf16(ax[m], brr[n], accR[m][n], 0, 0, 0);
            }
    }

    // epilogue: C/D layout col = lane&15, row = (lane>>4)*4 + reg
    int col_l = lane & 15;
    int row_l = (lane >> 4) * 4;
    #pragma unroll
    for (int n = 0; n < 2; ++n){
        int col = n0 + wc * 32 + n * 16 + col_l;
        float bb = b[col], rbb = rb[col];
        #pragma unroll
        for (int m = 0; m < 4; ++m){
            #pragma unroll
            for (int j = 0; j < 4; ++j){
                int row = m0 + wr * 64 + m * 16 + row_l + j;
                if (row < N_NODES){
                    float v = accS[m][n][j] + accG[m][n][j] + bb;
                    if (ACT) v = (v > 0.f) ? v : 0.01f * v;
                    v += accR[m][n][j] + rbb;
                    Y[(size_t)row * DO + col] = v;
                    if (DUAL2) Y2[(size_t)row * DO + col] = v;
                    if (WRITE_BF) YB[(size_t)row * DO + col] = f2b(v);
                }
            }
        }
    }
}

// ---------------- launch ----------------

extern "C" void kernel_launch(void* const* d_in, const int* in_sizes, int n_in,
                              void* d_out, int out_size, void* d_ws, size_t ws_size,
                              hipStream_t stream) {
    const int* edge  = (const int*)d_in[0];
    const int* e_src = edge;
    const int* e_dst = edge + N_EDGES;
    const float* w_pe = (const float*)d_in[1];
    const float* b_pe = (const float*)d_in[2];
    const float* ws0 = (const float*)d_in[3];
    const float* wn0 = (const float*)d_in[4];
    const float* b0  = (const float*)d_in[5];
    const float* wr0 = (const float*)d_in[6];
    const float* rb0 = (const float*)d_in[7];
    const float* ws1 = (const float*)d_in[8];
    const float* wn1 = (const float*)d_in[9];
    const float* b1  = (const float*)d_in[10];
    const float* wr1 = (const float*)d_in[11];
    const float* rb1 = (const float*)d_in[12];
    const float* ws2 = (const float*)d_in[13];
    const float* wn2 = (const float*)d_in[14];
    const float* b2  = (const float*)d_in[15];
    const float* wr2 = (const float*)d_in[16];
    const float* rb2 = (const float*)d_in[17];

    char* wsb = (char*)d_ws;
    ushort_t* h0   = (ushort_t*)wsb;                       // 10,240,000 B
    ushort_t* hb   = (ushort_t*)(wsb + 10240000);          // 10,240,000 B
    ushort_t* aggb = (ushort_t*)(wsb + 20480000);          // 10,240,000 B
    ushort_t* wbf  = (ushort_t*)(wsb + 30720000);          // 3,932,160 B
    int* deg     = (int*)(wsb + 34652160);                 // 10016 ints
    int* row_ptr = deg + 10016;
    int* cursor  = row_ptr + 10016;
    int* srcs    = cursor + 10016;                         // 320000 ints

    ushort_t* wbf0s = wbf;
    ushort_t* wbf0n = wbf + 262144;
    ushort_t* wbf0r = wbf + 524288;
    ushort_t* wbf1s = wbf + 786432;
    ushort_t* wbf1n = wbf + 1048576;
    ushort_t* wbf1r = wbf + 1310720;
    ushort_t* wbf2s = wbf + 1572864;
    ushort_t* wbf2n = wbf + 1703936;
    ushort_t* wbf2r = wbf + 1835008;

    float* out  = (float*)d_out;
    float* fin  = out;               // [10000][256]
    float* mid0 = out + 2560000;     // [10000][512]
    float* mid1 = out + 7680000;     // [10000][512]
    float* mid2 = out + 12800000;    // [10000][256]

    hipMemsetAsync(deg, 0, 10016 * sizeof(int), stream);
    k_degree <<<1250, 256, 0, stream>>>(e_dst, deg);
    k_scan   <<<1, 1024, 0, stream>>>(deg, row_ptr, cursor);
    k_scatter<<<1250, 256, 0, stream>>>(e_src, e_dst, cursor, srcs);

    CvtArgs ca;
    ca.s[0]=ws0; ca.s[1]=wn0; ca.s[2]=wr0;
    ca.s[3]=ws1; ca.s[4]=wn1; ca.s[5]=wr1;
    ca.s[6]=ws2; ca.s[7]=wn2; ca.s[8]=wr2;
    ca.d[0]=wbf0s; ca.d[1]=wbf0n; ca.d[2]=wbf0r;
    ca.d[3]=wbf1s; ca.d[4]=wbf1n; ca.d[5]=wbf1r;
    ca.d[6]=wbf2s; ca.d[7]=wbf2n; ca.d[8]=wbf2r;
    for (int i = 0; i < 6; ++i) ca.n[i] = 262144;
    for (int i = 6; i < 9; ++i) ca.n[i] = 131072;
    k_cvt<<<dim3(128, 9), 256, 0, stream>>>(ca);

    k_pe<<<dim3(157, 8), 256, 0, stream>>>(w_pe, b_pe, h0);

    k_agg<<<dim3(2500, 4), 256, 0, stream>>>(h0, row_ptr, srcs, aggb);
    k_layer<512, true,  false, true ><<<dim3(79, 8), 256, 0, stream>>>(
        h0, aggb, wbf0s, wbf0n, wbf0r, b0, rb0, mid0, nullptr, hb);

    k_agg<<<dim3(2500, 4), 256, 0, stream>>>(hb, row_ptr, srcs, aggb);
    k_layer<512, true,  false, true ><<<dim3(79, 8), 256, 0, stream>>>(
        hb, aggb, wbf1s, wbf1n, wbf1r, b1, rb1, mid1, nullptr, h0);

    k_agg<<<dim3(2500, 4), 256, 0, stream>>>(h0, row_ptr, srcs, aggb);
    k_layer<256, false, true,  false><<<dim3(79, 4), 256, 0, stream>>>(
        h0, aggb, wbf2s, wbf2n, wbf2r, b2, rb2, mid2, fin, nullptr);
}

// Round 5
// 305.623 us; speedup vs baseline: 1.0763x; 1.0763x over previous
//
#include <hip/hip_runtime.h>

#define N_NODES 10000
#define N_EDGES 320000
#define DIN 512
#define DHID 512
#define DOUT 256

typedef __bf16 bf16x8 __attribute__((ext_vector_type(8)));
typedef float f32x4 __attribute__((ext_vector_type(4)));
typedef unsigned short ushort_t;
typedef unsigned int uint_t;

__device__ __forceinline__ float b2f(ushort_t u){
    union { uint_t i; float f; } v; v.i = (uint_t)u << 16; return v.f;
}
__device__ __forceinline__ ushort_t f2b(float f){
    union { float f; uint_t i; } v; v.f = f;
    uint_t i = v.i;
    return (ushort_t)((i + 0x7fffu + ((i >> 16) & 1u)) >> 16); // RNE
}

__device__ __forceinline__ void gll16(const ushort_t* g, ushort_t* l){
    __builtin_amdgcn_global_load_lds(
        (const __attribute__((address_space(1))) unsigned int*)g,
        (__attribute__((address_space(3))) unsigned int*)l,
        16, 0, 0);
}

// ---------------- CSR build ----------------

__global__ void k_degree(const int* __restrict__ dst, int* __restrict__ deg){
    int e = blockIdx.x * 256 + threadIdx.x;
    if (e < N_EDGES) atomicAdd(&deg[dst[e]], 1);
}

__global__ void k_scan(const int* __restrict__ deg, int* __restrict__ row_ptr,
                       int* __restrict__ cursor){
    __shared__ int buf[1024];
    __shared__ int carry;
    int t = threadIdx.x;
    if (t == 0){ carry = 0; row_ptr[0] = 0; }
    __syncthreads();
    for (int c = 0; c < 10; ++c){
        int idx = c * 1024 + t;
        int v = (idx < N_NODES) ? deg[idx] : 0;
        buf[t] = v;
        __syncthreads();
        for (int off = 1; off < 1024; off <<= 1){
            int x = (t >= off) ? buf[t - off] : 0;
            __syncthreads();
            buf[t] += x;
            __syncthreads();
        }
        int inc = buf[t] + carry;   // inclusive prefix + carry
        if (idx < N_NODES){
            row_ptr[idx + 1] = inc;
            cursor[idx] = inc - v;  // exclusive prefix = bucket start
        }
        __syncthreads();
        if (t == 1023) carry = inc;
        __syncthreads();
    }
}

__global__ void k_scatter(const int* __restrict__ src, const int* __restrict__ dst,
                          int* __restrict__ cursor, int* __restrict__ srcs){
    int e = blockIdx.x * 256 + threadIdx.x;
    if (e < N_EDGES){
        int p = atomicAdd(&cursor[dst[e]], 1);
        srcs[p] = src[e];
    }
}

// ---------------- weight f32 -> bf16 conversion (once per call) ----------------

struct CvtArgs { const float* s[9]; ushort_t* d[9]; int n[9]; };

__global__ void k_cvt(CvtArgs a){
    int m = blockIdx.y;
    int i = (blockIdx.x * 256 + threadIdx.x) * 8;
    if (i < a.n[m]){
        const float* sp = a.s[m] + i;
        float4 f0 = *(const float4*)sp;
        float4 f1 = *(const float4*)(sp + 4);
        uint4 u;
        u.x = (uint_t)f2b(f0.x) | ((uint_t)f2b(f0.y) << 16);
        u.y = (uint_t)f2b(f0.z) | ((uint_t)f2b(f0.w) << 16);
        u.z = (uint_t)f2b(f1.x) | ((uint_t)f2b(f1.y) << 16);
        u.w = (uint_t)f2b(f1.z) | ((uint_t)f2b(f1.w) << 16);
        *(uint4*)&a.d[m][i] = u;
    }
}

// ---------------- pe = w_pe^T + b_pe (LDS tile transpose, f32 -> bf16) ----------------

__global__ void k_pe(const float* __restrict__ w_pe, const float* __restrict__ b_pe,
                     ushort_t* __restrict__ h0){
    __shared__ float lt[64][68];  // [n_local][i_local], padded
    int t = threadIdx.x;
    int n0 = blockIdx.x * 64, i0 = blockIdx.y * 64;
    int nc = (t & 15) * 4, ir = t >> 4;   // ir 0..15
    #pragma unroll
    for (int p = 0; p < 4; ++p){
        int i_loc = ir + p * 16;
        float4 v = {0.f, 0.f, 0.f, 0.f};
        if (n0 + nc < N_NODES)  // N_NODES % 4 == 0, chunk-level guard OK
            v = *(const float4*)&w_pe[(size_t)(i0 + i_loc) * N_NODES + n0 + nc];
        lt[nc + 0][i_loc] = v.x;
        lt[nc + 1][i_loc] = v.y;
        lt[nc + 2][i_loc] = v.z;
        lt[nc + 3][i_loc] = v.w;
    }
    __syncthreads();
    int ic = t & 7, nr = t >> 3;   // nr 0..31
    #pragma unroll
    for (int p = 0; p < 2; ++p){
        int n_loc = nr + p * 32;
        int n = n0 + n_loc;
        if (n < N_NODES){
            uint4 u;
            uint_t w01 = (uint_t)f2b(lt[n_loc][ic*8+0] + b_pe[i0+ic*8+0])
                       | ((uint_t)f2b(lt[n_loc][ic*8+1] + b_pe[i0+ic*8+1]) << 16);
            uint_t w23 = (uint_t)f2b(lt[n_loc][ic*8+2] + b_pe[i0+ic*8+2])
                       | ((uint_t)f2b(lt[n_loc][ic*8+3] + b_pe[i0+ic*8+3]) << 16);
            uint_t w45 = (uint_t)f2b(lt[n_loc][ic*8+4] + b_pe[i0+ic*8+4])
                       | ((uint_t)f2b(lt[n_loc][ic*8+5] + b_pe[i0+ic*8+5]) << 16);
            uint_t w67 = (uint_t)f2b(lt[n_loc][ic*8+6] + b_pe[i0+ic*8+6])
                       | ((uint_t)f2b(lt[n_loc][ic*8+7] + b_pe[i0+ic*8+7]) << 16);
            u.x = w01; u.y = w23; u.z = w45; u.w = w67;
            *(uint4*)&h0[(size_t)n * DIN + i0 + ic * 8] = u;
        }
    }
}

// ---------------- mean aggregation, panel-split for per-XCD L2 residency ----------------

__global__ __launch_bounds__(256) void k_agg(
    const ushort_t* __restrict__ X, const int* __restrict__ row_ptr,
    const int* __restrict__ srcs, ushort_t* __restrict__ out)
{
    int w = threadIdx.x >> 6, lane = threadIdx.x & 63;
    int n = blockIdx.x * 4 + w;
    int col = blockIdx.y * 128 + lane * 2;
    int beg = row_ptr[n], end = row_ptr[n + 1];
    float a0 = 0.f, a1 = 0.f;
    int j = beg;
    for (; j + 4 <= end; j += 4){
        int s0 = srcs[j + 0], s1 = srcs[j + 1], s2 = srcs[j + 2], s3 = srcs[j + 3];
        uint_t v0 = *(const uint_t*)&X[(size_t)s0 * 512 + col];
        uint_t v1 = *(const uint_t*)&X[(size_t)s1 * 512 + col];
        uint_t v2 = *(const uint_t*)&X[(size_t)s2 * 512 + col];
        uint_t v3 = *(const uint_t*)&X[(size_t)s3 * 512 + col];
        a0 += b2f((ushort_t)(v0 & 0xffffu)); a1 += b2f((ushort_t)(v0 >> 16));
        a0 += b2f((ushort_t)(v1 & 0xffffu)); a1 += b2f((ushort_t)(v1 >> 16));
        a0 += b2f((ushort_t)(v2 & 0xffffu)); a1 += b2f((ushort_t)(v2 >> 16));
        a0 += b2f((ushort_t)(v3 & 0xffffu)); a1 += b2f((ushort_t)(v3 >> 16));
    }
    for (; j < end; ++j){
        int s = srcs[j];
        uint_t v = *(const uint_t*)&X[(size_t)s * 512 + col];
        a0 += b2f((ushort_t)(v & 0xffffu)); a1 += b2f((ushort_t)(v >> 16));
    }
    float inv = (end > beg) ? 1.f / (float)(end - beg) : 1.f;
    uint_t o = (uint_t)f2b(a0 * inv) | ((uint_t)f2b(a1 * inv) << 16);
    *(uint_t*)&out[(size_t)n * 512 + col] = o;
}

// ---------------- fused SAGE layer: 2-phase pipeline + XCD-grouped blocks ----------------
// BM=128, BN=64, BK=32; 4 waves (2x2), wave tile 64x32; global_load_lds 16B staging,
// double-buffered LDS (56KB), one barrier per K-step. Blocks sharing an m-tile are
// placed on the same XCD (bid%8 = m%8) so X/G panels are fetched ~once chip-wide.
// Y(f32) = [leaky?](X@Ws^T + Agg@Wn^T + b) + X@Wr^T + rb

template<int DO, bool ACT, bool DUAL2, bool WRITE_BF>
__global__ __launch_bounds__(256) void k_layer(
    const ushort_t* __restrict__ X, const ushort_t* __restrict__ G,
    const ushort_t* __restrict__ Ws, const ushort_t* __restrict__ Wn,
    const ushort_t* __restrict__ Wr,
    const float* __restrict__ b, const float* __restrict__ rb,
    float* __restrict__ Y, float* __restrict__ Y2, ushort_t* __restrict__ YB)
{
    // per 28KB buffer (ushort offsets): X:[0,4096) G:[4096,8192) Ws:[8192,10240)
    // Wn:[10240,12288) Wr:[12288,14336)  — rows of 32 elems (64B), linear for gll16
    __shared__ __align__(16) ushort_t smem[2][14336];

    int t = threadIdx.x;
    constexpr int NT = DO / 64;
    int bid = blockIdx.x;
    int r8 = bid & 7, q = bid >> 3;
    int m_t = (q / NT) * 8 + r8;
    int n_t = q % NT;
    if (m_t * 128 >= N_NODES) return;   // whole-block OOB (uniform)
    int m0 = m_t * 128, n0 = n_t * 64;

    int lane = t & 63, w = t >> 6;
    int wr = w >> 1, wc = w & 1;           // wave tile: rows wr*64, cols wc*32

    // staging: 28 chunks of 1KB (16 rows x 64B), 7 per wave
    const ushort_t* gptr[7];
    int coff[7];
    int rl = lane >> 2, sl = (lane & 3) * 8;
    #pragma unroll
    for (int i = 0; i < 7; ++i){
        int qq = w * 7 + i;
        const ushort_t* gA; int rowbase, off;
        if (qq < 8)       { gA = X;  rowbase = m0 + qq * 16;        off = qq * 512; }
        else if (qq < 16) { gA = G;  rowbase = m0 + (qq - 8) * 16;  off = 4096 + (qq - 8) * 512; }
        else if (qq < 20) { gA = Ws; rowbase = n0 + (qq - 16) * 16; off = 8192 + (qq - 16) * 512; }
        else if (qq < 24) { gA = Wn; rowbase = n0 + (qq - 20) * 16; off = 10240 + (qq - 20) * 512; }
        else              { gA = Wr; rowbase = n0 + (qq - 24) * 16; off = 12288 + (qq - 24) * 512; }
        gptr[i] = gA + (size_t)(rowbase + rl) * 512 + sl;
        coff[i] = off;   // wave-uniform; HW writes base + lane*16B
    }

    f32x4 accS[4][2] = {}, accG[4][2] = {}, accR[4][2] = {};
    int arow = wr * 64 + (lane & 15);
    int brow = wc * 32 + (lane & 15);
    int kk = (lane >> 4) * 8;

    // prologue: stage K-step 0 into buffer 0
    #pragma unroll
    for (int i = 0; i < 7; ++i) gll16(gptr[i], &smem[0][coff[i]]);
    __syncthreads();   // compiler drains vmcnt before s_barrier

    int cur = 0;
    for (int ks = 0; ks < 16; ++ks){
        // issue next tile's stage BEFORE compute (hidden under MFMA)
        if (ks < 15){
            int k0 = (ks + 1) * 32;
            #pragma unroll
            for (int i = 0; i < 7; ++i) gll16(gptr[i] + k0, &smem[cur ^ 1][coff[i]]);
        }

        const ushort_t* sb = smem[cur];
        bf16x8 ax[4], ag[4], bs[2], bn_[2], brr[2];
        #pragma unroll
        for (int m = 0; m < 4; ++m){
            ax[m] = *(const bf16x8*)&sb[(arow + m * 16) * 32 + kk];
            ag[m] = *(const bf16x8*)&sb[4096 + (arow + m * 16) * 32 + kk];
        }
        #pragma unroll
        for (int n = 0; n < 2; ++n){
            bs[n]  = *(const bf16x8*)&sb[8192  + (brow + n * 16) * 32 + kk];
            bn_[n] = *(const bf16x8*)&sb[10240 + (brow + n * 16) * 32 + kk];
            brr[n] = *(const bf16x8*)&sb[12288 + (brow + n * 16) * 32 + kk];
        }
        #pragma unroll
        for (int m = 0; m < 4; ++m)
            #pragma unroll
            for (int n = 0; n < 2; ++n){
                accS[m][n] = __builtin_amdgcn_mfma_f32_16x16x32_bf16(ax[m], bs[n],  accS[m][n], 0, 0, 0);
                accG[m][n] = __builtin_amdgcn_mfma_f32_16x16x32_bf16(ag[m], bn_[n], accG[m][n], 0, 0, 0);
                accR[m][n] = __builtin_amdgcn_mfma_f32_16x16x32_bf16(ax[m], brr[n], accR[m][n], 0, 0, 0);
            }

        __syncthreads();   // drains vmcnt(0): next buffer staged; all waves done reading cur
        cur ^= 1;
    }

    // epilogue: C/D layout col = lane&15, row = (lane>>4)*4 + reg
    int col_l = lane & 15;
    int row_l = (lane >> 4) * 4;
    #pragma unroll
    for (int n = 0; n < 2; ++n){
        int col = n0 + wc * 32 + n * 16 + col_l;
        float bb = b[col], rbb = rb[col];
        #pragma unroll
        for (int m = 0; m < 4; ++m){
            #pragma unroll
            for (int j = 0; j < 4; ++j){
                int row = m0 + wr * 64 + m * 16 + row_l + j;
                if (row < N_NODES){
                    float v = accS[m][n][j] + accG[m][n][j] + bb;
                    if (ACT) v = (v > 0.f) ? v : 0.01f * v;
                    v += accR[m][n][j] + rbb;
                    Y[(size_t)row * DO + col] = v;
                    if (DUAL2) Y2[(size_t)row * DO + col] = v;
                    if (WRITE_BF) YB[(size_t)row * DO + col] = f2b(v);
                }
            }
        }
    }
}

// ---------------- launch ----------------

extern "C" void kernel_launch(void* const* d_in, const int* in_sizes, int n_in,
                              void* d_out, int out_size, void* d_ws, size_t ws_size,
                              hipStream_t stream) {
    const int* edge  = (const int*)d_in[0];
    const int* e_src = edge;
    const int* e_dst = edge + N_EDGES;
    const float* w_pe = (const float*)d_in[1];
    const float* b_pe = (const float*)d_in[2];
    const float* ws0 = (const float*)d_in[3];
    const float* wn0 = (const float*)d_in[4];
    const float* b0  = (const float*)d_in[5];
    const float* wr0 = (const float*)d_in[6];
    const float* rb0 = (const float*)d_in[7];
    const float* ws1 = (const float*)d_in[8];
    const float* wn1 = (const float*)d_in[9];
    const float* b1  = (const float*)d_in[10];
    const float* wr1 = (const float*)d_in[11];
    const float* rb1 = (const float*)d_in[12];
    const float* ws2 = (const float*)d_in[13];
    const float* wn2 = (const float*)d_in[14];
    const float* b2  = (const float*)d_in[15];
    const float* wr2 = (const float*)d_in[16];
    const float* rb2 = (const float*)d_in[17];

    char* wsb = (char*)d_ws;
    ushort_t* h0   = (ushort_t*)wsb;                       // 10,240,000 B
    ushort_t* hb   = (ushort_t*)(wsb + 10240000);          // 10,240,000 B
    ushort_t* aggb = (ushort_t*)(wsb + 20480000);          // 10,240,000 B
    ushort_t* wbf  = (ushort_t*)(wsb + 30720000);          // 3,932,160 B
    int* deg     = (int*)(wsb + 34652160);                 // 10016 ints
    int* row_ptr = deg + 10016;
    int* cursor  = row_ptr + 10016;
    int* srcs    = cursor + 10016;                         // 320000 ints

    ushort_t* wbf0s = wbf;
    ushort_t* wbf0n = wbf + 262144;
    ushort_t* wbf0r = wbf + 524288;
    ushort_t* wbf1s = wbf + 786432;
    ushort_t* wbf1n = wbf + 1048576;
    ushort_t* wbf1r = wbf + 1310720;
    ushort_t* wbf2s = wbf + 1572864;
    ushort_t* wbf2n = wbf + 1703936;
    ushort_t* wbf2r = wbf + 1835008;

    float* out  = (float*)d_out;
    float* fin  = out;               // [10000][256]
    float* mid0 = out + 2560000;     // [10000][512]
    float* mid1 = out + 7680000;     // [10000][512]
    float* mid2 = out + 12800000;    // [10000][256]

    hipMemsetAsync(deg, 0, 10016 * sizeof(int), stream);
    k_degree <<<1250, 256, 0, stream>>>(e_dst, deg);
    k_scan   <<<1, 1024, 0, stream>>>(deg, row_ptr, cursor);
    k_scatter<<<1250, 256, 0, stream>>>(e_src, e_dst, cursor, srcs);

    CvtArgs ca;
    ca.s[0]=ws0; ca.s[1]=wn0; ca.s[2]=wr0;
    ca.s[3]=ws1; ca.s[4]=wn1; ca.s[5]=wr1;
    ca.s[6]=ws2; ca.s[7]=wn2; ca.s[8]=wr2;
    ca.d[0]=wbf0s; ca.d[1]=wbf0n; ca.d[2]=wbf0r;
    ca.d[3]=wbf1s; ca.d[4]=wbf1n; ca.d[5]=wbf1r;
    ca.d[6]=wbf2s; ca.d[7]=wbf2n; ca.d[8]=wbf2r;
    for (int i = 0; i < 6; ++i) ca.n[i] = 262144;
    for (int i = 6; i < 9; ++i) ca.n[i] = 131072;
    k_cvt<<<dim3(128, 9), 256, 0, stream>>>(ca);

    k_pe<<<dim3(157, 8), 256, 0, stream>>>(w_pe, b_pe, h0);

    // grid: 8 xcd-residues * NT n-tiles * 10 m-groups
    k_agg<<<dim3(2500, 4), 256, 0, stream>>>(h0, row_ptr, srcs, aggb);
    k_layer<512, true,  false, true ><<<dim3(640), 256, 0, stream>>>(
        h0, aggb, wbf0s, wbf0n, wbf0r, b0, rb0, mid0, nullptr, hb);

    k_agg<<<dim3(2500, 4), 256, 0, stream>>>(hb, row_ptr, srcs, aggb);
    k_layer<512, true,  false, true ><<<dim3(640), 256, 0, stream>>>(
        hb, aggb, wbf1s, wbf1n, wbf1r, b1, rb1, mid1, nullptr, h0);

    k_agg<<<dim3(2500, 4), 256, 0, stream>>>(h0, row_ptr, srcs, aggb);
    k_layer<256, false, true,  false><<<dim3(320), 256, 0, stream>>>(
        h0, aggb, wbf2s, wbf2n, wbf2r, b2, rb2, mid2, fin, nullptr);
}

// Round 6
// 277.865 us; speedup vs baseline: 1.1838x; 1.0999x over previous
//
#include <hip/hip_runtime.h>

#define N_NODES 10000
#define N_EDGES 320000
#define DIN 512
#define DHID 512
#define DOUT 256

typedef __bf16 bf16x8 __attribute__((ext_vector_type(8)));
typedef float f32x4 __attribute__((ext_vector_type(4)));
typedef unsigned short ushort_t;
typedef unsigned int uint_t;

__device__ __forceinline__ float b2f(ushort_t u){
    union { uint_t i; float f; } v; v.i = (uint_t)u << 16; return v.f;
}
__device__ __forceinline__ ushort_t f2b(float f){
    union { float f; uint_t i; } v; v.f = f;
    uint_t i = v.i;
    return (ushort_t)((i + 0x7fffu + ((i >> 16) & 1u)) >> 16); // RNE
}

__device__ __forceinline__ void gll16(const ushort_t* g, ushort_t* l){
    __builtin_amdgcn_global_load_lds(
        (const __attribute__((address_space(1))) unsigned int*)g,
        (__attribute__((address_space(3))) unsigned int*)l,
        16, 0, 0);
}

// ---------------- CSR build ----------------

__global__ void k_degree(const int* __restrict__ dst, int* __restrict__ deg){
    int e = blockIdx.x * 256 + threadIdx.x;
    if (e < N_EDGES) atomicAdd(&deg[dst[e]], 1);
}

// 256 threads, 40 elems/thread serial scan in regs + 8-round block scan.
__global__ void k_scan(const int* __restrict__ deg, int* __restrict__ row_ptr,
                       int* __restrict__ cursor){
    __shared__ int part[256];
    int t = threadIdx.x;
    int base = t * 40;
    int loc[40];
    int s = 0;
    #pragma unroll
    for (int i = 0; i < 40; ++i){
        int idx = base + i;
        int v = (idx < N_NODES) ? deg[idx] : 0;
        s += v; loc[i] = s;          // thread-local inclusive
    }
    part[t] = s;
    __syncthreads();
    int val = s;
    for (int off = 1; off < 256; off <<= 1){
        int x = (t >= off) ? part[t - off] : 0;
        __syncthreads();
        val += x; part[t] = val;
        __syncthreads();
    }
    int exc = val - s;               // exclusive prefix of this thread's chunk
    if (t == 0) row_ptr[0] = 0;
    int run = exc;
    #pragma unroll
    for (int i = 0; i < 40; ++i){
        int idx = base + i;
        if (idx < N_NODES){
            row_ptr[idx + 1] = exc + loc[i];
            cursor[idx] = run;       // bucket start (exclusive)
        }
        run = exc + loc[i];
    }
}

__global__ void k_scatter(const int* __restrict__ src, const int* __restrict__ dst,
                          int* __restrict__ cursor, int* __restrict__ srcs){
    int e = blockIdx.x * 256 + threadIdx.x;
    if (e < N_EDGES){
        int p = atomicAdd(&cursor[dst[e]], 1);
        srcs[p] = src[e];
    }
}

// ---------------- weight f32 -> bf16 conversion (once per call) ----------------

struct CvtArgs { const float* s[9]; ushort_t* d[9]; int n[9]; };

__global__ void k_cvt(CvtArgs a){
    int m = blockIdx.y;
    int i = (blockIdx.x * 256 + threadIdx.x) * 8;
    if (i < a.n[m]){
        const float* sp = a.s[m] + i;
        float4 f0 = *(const float4*)sp;
        float4 f1 = *(const float4*)(sp + 4);
        uint4 u;
        u.x = (uint_t)f2b(f0.x) | ((uint_t)f2b(f0.y) << 16);
        u.y = (uint_t)f2b(f0.z) | ((uint_t)f2b(f0.w) << 16);
        u.z = (uint_t)f2b(f1.x) | ((uint_t)f2b(f1.y) << 16);
        u.w = (uint_t)f2b(f1.z) | ((uint_t)f2b(f1.w) << 16);
        *(uint4*)&a.d[m][i] = u;
    }
}

// ---------------- pe = w_pe^T + b_pe (LDS tile transpose, f32 -> bf16) ----------------

__global__ void k_pe(const float* __restrict__ w_pe, const float* __restrict__ b_pe,
                     ushort_t* __restrict__ h0){
    __shared__ float lt[64][68];  // [n_local][i_local], padded
    int t = threadIdx.x;
    int n0 = blockIdx.x * 64, i0 = blockIdx.y * 64;
    int nc = (t & 15) * 4, ir = t >> 4;   // ir 0..15
    #pragma unroll
    for (int p = 0; p < 4; ++p){
        int i_loc = ir + p * 16;
        float4 v = {0.f, 0.f, 0.f, 0.f};
        if (n0 + nc < N_NODES)
            v = *(const float4*)&w_pe[(size_t)(i0 + i_loc) * N_NODES + n0 + nc];
        lt[nc + 0][i_loc] = v.x;
        lt[nc + 1][i_loc] = v.y;
        lt[nc + 2][i_loc] = v.z;
        lt[nc + 3][i_loc] = v.w;
    }
    __syncthreads();
    int ic = t & 7, nr = t >> 3;   // nr 0..31
    #pragma unroll
    for (int p = 0; p < 2; ++p){
        int n_loc = nr + p * 32;
        int n = n0 + n_loc;
        if (n < N_NODES){
            uint4 u;
            uint_t w01 = (uint_t)f2b(lt[n_loc][ic*8+0] + b_pe[i0+ic*8+0])
                       | ((uint_t)f2b(lt[n_loc][ic*8+1] + b_pe[i0+ic*8+1]) << 16);
            uint_t w23 = (uint_t)f2b(lt[n_loc][ic*8+2] + b_pe[i0+ic*8+2])
                       | ((uint_t)f2b(lt[n_loc][ic*8+3] + b_pe[i0+ic*8+3]) << 16);
            uint_t w45 = (uint_t)f2b(lt[n_loc][ic*8+4] + b_pe[i0+ic*8+4])
                       | ((uint_t)f2b(lt[n_loc][ic*8+5] + b_pe[i0+ic*8+5]) << 16);
            uint_t w67 = (uint_t)f2b(lt[n_loc][ic*8+6] + b_pe[i0+ic*8+6])
                       | ((uint_t)f2b(lt[n_loc][ic*8+7] + b_pe[i0+ic*8+7]) << 16);
            u.x = w01; u.y = w23; u.z = w45; u.w = w67;
            *(uint4*)&h0[(size_t)n * DIN + i0 + ic * 8] = u;
        }
    }
}

// ---------------- mean aggregation, panel-split for per-XCD L2 residency ----------------

__global__ __launch_bounds__(256) void k_agg(
    const ushort_t* __restrict__ X, const int* __restrict__ row_ptr,
    const int* __restrict__ srcs, ushort_t* __restrict__ out)
{
    int w = threadIdx.x >> 6, lane = threadIdx.x & 63;
    int n = blockIdx.x * 4 + w;
    int col = blockIdx.y * 128 + lane * 2;
    int beg = row_ptr[n], end = row_ptr[n + 1];
    float a0 = 0.f, a1 = 0.f;
    int j = beg;
    for (; j + 4 <= end; j += 4){
        int s0 = srcs[j + 0], s1 = srcs[j + 1], s2 = srcs[j + 2], s3 = srcs[j + 3];
        uint_t v0 = *(const uint_t*)&X[(size_t)s0 * 512 + col];
        uint_t v1 = *(const uint_t*)&X[(size_t)s1 * 512 + col];
        uint_t v2 = *(const uint_t*)&X[(size_t)s2 * 512 + col];
        uint_t v3 = *(const uint_t*)&X[(size_t)s3 * 512 + col];
        a0 += b2f((ushort_t)(v0 & 0xffffu)); a1 += b2f((ushort_t)(v0 >> 16));
        a0 += b2f((ushort_t)(v1 & 0xffffu)); a1 += b2f((ushort_t)(v1 >> 16));
        a0 += b2f((ushort_t)(v2 & 0xffffu)); a1 += b2f((ushort_t)(v2 >> 16));
        a0 += b2f((ushort_t)(v3 & 0xffffu)); a1 += b2f((ushort_t)(v3 >> 16));
    }
    for (; j < end; ++j){
        int s = srcs[j];
        uint_t v = *(const uint_t*)&X[(size_t)s * 512 + col];
        a0 += b2f((ushort_t)(v & 0xffffu)); a1 += b2f((ushort_t)(v >> 16));
    }
    float inv = (end > beg) ? 1.f / (float)(end - beg) : 1.f;
    uint_t o = (uint_t)f2b(a0 * inv) | ((uint_t)f2b(a1 * inv) << 16);
    *(uint_t*)&out[(size_t)n * 512 + col] = o;
}

// ---------------- fused SAGE layer: one-batch BM=160 geometry ----------------
// BM=160, BN=64, BK=32; 4 waves (2x2), wave tile 80x64 (5x2 MFMA blocks);
// LDS 64KB double-buffered -> exactly 2 blocks/CU; grid 504(DHID)/252(DOUT) jobs
// <= 512 capacity: the whole layer is ONE co-resident batch (no tail).
// Blocks sharing an m-tile land on the same XCD (bid%8 = m%8).
// Y(f32) = [leaky?](X@Ws^T + Agg@Wn^T + b) + X@Wr^T + rb

template<int DO, bool ACT, bool DUAL2, bool WRITE_BF>
__global__ __launch_bounds__(256, 2) void k_layer(
    const ushort_t* __restrict__ X, const ushort_t* __restrict__ G,
    const ushort_t* __restrict__ Ws, const ushort_t* __restrict__ Wn,
    const ushort_t* __restrict__ Wr,
    const float* __restrict__ b, const float* __restrict__ rb,
    float* __restrict__ Y, float* __restrict__ Y2, ushort_t* __restrict__ YB)
{
    // per 32KB buffer (ushort offsets): X:[0,5120) G:[5120,10240) Ws:[10240,12288)
    // Wn:[12288,14336) Wr:[14336,16384)  — rows of 32 elems (64B), linear for gll16
    __shared__ __align__(16) ushort_t smem[2][16384];

    int t = threadIdx.x;
    constexpr int NT = DO / 64;
    int bid = blockIdx.x;
    int r8 = bid & 7, q = bid >> 3;
    int m_t = (q / NT) * 8 + r8;
    int n_t = q % NT;
    if (m_t * 160 >= N_NODES) return;   // uniform whole-block guard
    int m0 = m_t * 160, n0 = n_t * 64;

    int lane = t & 63, w = t >> 6;
    int wr = w >> 1, wc = w & 1;        // wave tile: rows wr*80, cols wc*32

    // staging: 32 chunks of 1KB (16 rows x 64B), 8 per wave
    const ushort_t* gptr[8];
    int coff[8];
    int rl = lane >> 2, sl = (lane & 3) * 8;
    #pragma unroll
    for (int i = 0; i < 8; ++i){
        int qq = w * 8 + i;
        const ushort_t* gA; int rowbase, off;
        if (qq < 10)      { gA = X;  rowbase = m0 + qq * 16;        off = qq * 512; }
        else if (qq < 20) { gA = G;  rowbase = m0 + (qq - 10) * 16; off = 5120 + (qq - 10) * 512; }
        else if (qq < 24) { gA = Ws; rowbase = n0 + (qq - 20) * 16; off = 10240 + (qq - 20) * 512; }
        else if (qq < 28) { gA = Wn; rowbase = n0 + (qq - 24) * 16; off = 12288 + (qq - 24) * 512; }
        else              { gA = Wr; rowbase = n0 + (qq - 28) * 16; off = 14336 + (qq - 28) * 512; }
        gptr[i] = gA + (size_t)(rowbase + rl) * 512 + sl;
        coff[i] = off;   // wave-uniform; HW writes base + lane*16B
    }

    f32x4 accS[5][2] = {}, accG[5][2] = {}, accR[5][2] = {};
    int arow = wr * 80 + (lane & 15);
    int brow = wc * 32 + (lane & 15);
    int kk = (lane >> 4) * 8;

    // prologue: stage K-step 0 into buffer 0
    #pragma unroll
    for (int i = 0; i < 8; ++i) gll16(gptr[i], &smem[0][coff[i]]);
    __syncthreads();

    int cur = 0;
    for (int ks = 0; ks < 16; ++ks){
        if (ks < 15){
            int k0 = (ks + 1) * 32;
            #pragma unroll
            for (int i = 0; i < 8; ++i) gll16(gptr[i] + k0, &smem[cur ^ 1][coff[i]]);
        }

        const ushort_t* sb = smem[cur];
        bf16x8 ax[5], ag[5], bs[2], bn_[2], brr[2];
        #pragma unroll
        for (int m = 0; m < 5; ++m){
            ax[m] = *(const bf16x8*)&sb[(arow + m * 16) * 32 + kk];
            ag[m] = *(const bf16x8*)&sb[5120 + (arow + m * 16) * 32 + kk];
        }
        #pragma unroll
        for (int n = 0; n < 2; ++n){
            bs[n]  = *(const bf16x8*)&sb[10240 + (brow + n * 16) * 32 + kk];
            bn_[n] = *(const bf16x8*)&sb[12288 + (brow + n * 16) * 32 + kk];
            brr[n] = *(const bf16x8*)&sb[14336 + (brow + n * 16) * 32 + kk];
        }
        #pragma unroll
        for (int m = 0; m < 5; ++m)
            #pragma unroll
            for (int n = 0; n < 2; ++n){
                accS[m][n] = __builtin_amdgcn_mfma_f32_16x16x32_bf16(ax[m], bs[n],  accS[m][n], 0, 0, 0);
                accG[m][n] = __builtin_amdgcn_mfma_f32_16x16x32_bf16(ag[m], bn_[n], accG[m][n], 0, 0, 0);
                accR[m][n] = __builtin_amdgcn_mfma_f32_16x16x32_bf16(ax[m], brr[n], accR[m][n], 0, 0, 0);
            }

        __syncthreads();   // next buffer staged; all waves done reading cur
        cur ^= 1;
    }

    // epilogue: C/D layout col = lane&15, row = (lane>>4)*4 + reg
    int col_l = lane & 15;
    int row_l = (lane >> 4) * 4;
    #pragma unroll
    for (int n = 0; n < 2; ++n){
        int col = n0 + wc * 32 + n * 16 + col_l;
        float bb = b[col], rbb = rb[col];
        #pragma unroll
        for (int m = 0; m < 5; ++m){
            #pragma unroll
            for (int j = 0; j < 4; ++j){
                int row = m0 + wr * 80 + m * 16 + row_l + j;
                if (row < N_NODES){
                    float v = accS[m][n][j] + accG[m][n][j] + bb;
                    if (ACT) v = (v > 0.f) ? v : 0.01f * v;
                    v += accR[m][n][j] + rbb;
                    Y[(size_t)row * DO + col] = v;
                    if (DUAL2) Y2[(size_t)row * DO + col] = v;
                    if (WRITE_BF) YB[(size_t)row * DO + col] = f2b(v);
                }
            }
        }
    }
}

// ---------------- launch ----------------

extern "C" void kernel_launch(void* const* d_in, const int* in_sizes, int n_in,
                              void* d_out, int out_size, void* d_ws, size_t ws_size,
                              hipStream_t stream) {
    const int* edge  = (const int*)d_in[0];
    const int* e_src = edge;
    const int* e_dst = edge + N_EDGES;
    const float* w_pe = (const float*)d_in[1];
    const float* b_pe = (const float*)d_in[2];
    const float* ws0 = (const float*)d_in[3];
    const float* wn0 = (const float*)d_in[4];
    const float* b0  = (const float*)d_in[5];
    const float* wr0 = (const float*)d_in[6];
    const float* rb0 = (const float*)d_in[7];
    const float* ws1 = (const float*)d_in[8];
    const float* wn1 = (const float*)d_in[9];
    const float* b1  = (const float*)d_in[10];
    const float* wr1 = (const float*)d_in[11];
    const float* rb1 = (const float*)d_in[12];
    const float* ws2 = (const float*)d_in[13];
    const float* wn2 = (const float*)d_in[14];
    const float* b2  = (const float*)d_in[15];
    const float* wr2 = (const float*)d_in[16];
    const float* rb2 = (const float*)d_in[17];

    char* wsb = (char*)d_ws;
    ushort_t* h0   = (ushort_t*)wsb;                       // 10,240,000 B
    ushort_t* hb   = (ushort_t*)(wsb + 10240000);          // 10,240,000 B
    ushort_t* aggb = (ushort_t*)(wsb + 20480000);          // 10,240,000 B
    ushort_t* wbf  = (ushort_t*)(wsb + 30720000);          // 3,932,160 B
    int* deg     = (int*)(wsb + 34652160);                 // 10016 ints
    int* row_ptr = deg + 10016;
    int* cursor  = row_ptr + 10016;
    int* srcs    = cursor + 10016;                         // 320000 ints

    ushort_t* wbf0s = wbf;
    ushort_t* wbf0n = wbf + 262144;
    ushort_t* wbf0r = wbf + 524288;
    ushort_t* wbf1s = wbf + 786432;
    ushort_t* wbf1n = wbf + 1048576;
    ushort_t* wbf1r = wbf + 1310720;
    ushort_t* wbf2s = wbf + 1572864;
    ushort_t* wbf2n = wbf + 1703936;
    ushort_t* wbf2r = wbf + 1835008;

    float* out  = (float*)d_out;
    float* fin  = out;               // [10000][256]
    float* mid0 = out + 2560000;     // [10000][512]
    float* mid1 = out + 7680000;     // [10000][512]
    float* mid2 = out + 12800000;    // [10000][256]

    hipMemsetAsync(deg, 0, 10016 * sizeof(int), stream);
    k_degree <<<1250, 256, 0, stream>>>(e_dst, deg);
    k_scan   <<<1, 256, 0, stream>>>(deg, row_ptr, cursor);
    k_scatter<<<1250, 256, 0, stream>>>(e_src, e_dst, cursor, srcs);

    CvtArgs ca;
    ca.s[0]=ws0; ca.s[1]=wn0; ca.s[2]=wr0;
    ca.s[3]=ws1; ca.s[4]=wn1; ca.s[5]=wr1;
    ca.s[6]=ws2; ca.s[7]=wn2; ca.s[8]=wr2;
    ca.d[0]=wbf0s; ca.d[1]=wbf0n; ca.d[2]=wbf0r;
    ca.d[3]=wbf1s; ca.d[4]=wbf1n; ca.d[5]=wbf1r;
    ca.d[6]=wbf2s; ca.d[7]=wbf2n; ca.d[8]=wbf2r;
    for (int i = 0; i < 6; ++i) ca.n[i] = 262144;
    for (int i = 6; i < 9; ++i) ca.n[i] = 131072;
    k_cvt<<<dim3(128, 9), 256, 0, stream>>>(ca);

    k_pe<<<dim3(157, 8), 256, 0, stream>>>(w_pe, b_pe, h0);

    // grid: 8 xcd-residues * NT n-tiles * 8 m-groups (BM=160: 63 m-tiles + guard)
    k_agg<<<dim3(2500, 4), 256, 0, stream>>>(h0, row_ptr, srcs, aggb);
    k_layer<512, true,  false, true ><<<dim3(512), 256, 0, stream>>>(
        h0, aggb, wbf0s, wbf0n, wbf0r, b0, rb0, mid0, nullptr, hb);

    k_agg<<<dim3(2500, 4), 256, 0, stream>>>(hb, row_ptr, srcs, aggb);
    k_layer<512, true,  false, true ><<<dim3(512), 256, 0, stream>>>(
        hb, aggb, wbf1s, wbf1n, wbf1r, b1, rb1, mid1, nullptr, h0);

    k_agg<<<dim3(2500, 4), 256, 0, stream>>>(h0, row_ptr, srcs, aggb);
    k_layer<256, false, true,  false><<<dim3(256), 256, 0, stream>>>(
        h0, aggb, wbf2s, wbf2n, wbf2r, b2, rb2, mid2, fin, nullptr);
}

// Round 7
// 252.021 us; speedup vs baseline: 1.3052x; 1.1025x over previous
//
#include <hip/hip_runtime.h>

#define N_NODES 10000
#define N_EDGES 320000
#define DIN 512
#define DHID 512
#define DOUT 256

typedef __bf16 bf16x8 __attribute__((ext_vector_type(8)));
typedef float f32x4 __attribute__((ext_vector_type(4)));
typedef unsigned short ushort_t;
typedef unsigned int uint_t;

__device__ __forceinline__ float b2f(ushort_t u){
    union { uint_t i; float f; } v; v.i = (uint_t)u << 16; return v.f;
}
__device__ __forceinline__ float blo(uint_t v){
    union { uint_t i; float f; } u; u.i = v << 16; return u.f;
}
__device__ __forceinline__ float bhi(uint_t v){
    union { uint_t i; float f; } u; u.i = v & 0xffff0000u; return u.f;
}
__device__ __forceinline__ ushort_t f2b(float f){
    union { float f; uint_t i; } v; v.f = f;
    uint_t i = v.i;
    return (ushort_t)((i + 0x7fffu + ((i >> 16) & 1u)) >> 16); // RNE
}

__device__ __forceinline__ void gll16(const ushort_t* g, ushort_t* l){
    __builtin_amdgcn_global_load_lds(
        (const __attribute__((address_space(1))) unsigned int*)g,
        (__attribute__((address_space(3))) unsigned int*)l,
        16, 0, 0);
}

// ---------------- CSR build ----------------

__global__ void k_zero(int* __restrict__ p){
    int i = blockIdx.x * 256 + threadIdx.x;
    if (i < N_NODES) p[i] = 0;
}

__global__ void k_degree(const int* __restrict__ dst, int* __restrict__ deg){
    int e = blockIdx.x * 256 + threadIdx.x;
    if (e < N_EDGES) atomicAdd(&deg[dst[e]], 1);
}

// 256 threads, 40 elems/thread serial scan in regs + 8-round block scan.
__global__ void k_scan(const int* __restrict__ deg, int* __restrict__ row_ptr,
                       int* __restrict__ cursor){
    __shared__ int part[256];
    int t = threadIdx.x;
    int base = t * 40;
    int loc[40];
    int s = 0;
    #pragma unroll
    for (int i = 0; i < 40; ++i){
        int idx = base + i;
        int v = (idx < N_NODES) ? deg[idx] : 0;
        s += v; loc[i] = s;          // thread-local inclusive
    }
    part[t] = s;
    __syncthreads();
    int val = s;
    for (int off = 1; off < 256; off <<= 1){
        int x = (t >= off) ? part[t - off] : 0;
        __syncthreads();
        val += x; part[t] = val;
        __syncthreads();
    }
    int exc = val - s;               // exclusive prefix of this thread's chunk
    if (t == 0) row_ptr[0] = 0;
    int run = exc;
    #pragma unroll
    for (int i = 0; i < 40; ++i){
        int idx = base + i;
        if (idx < N_NODES){
            row_ptr[idx + 1] = exc + loc[i];
            cursor[idx] = run;       // bucket start (exclusive)
        }
        run = exc + loc[i];
    }
}

__global__ void k_scatter(const int* __restrict__ src, const int* __restrict__ dst,
                          int* __restrict__ cursor, int* __restrict__ srcs){
    int e = blockIdx.x * 256 + threadIdx.x;
    if (e < N_EDGES){
        int p = atomicAdd(&cursor[dst[e]], 1);
        srcs[p] = src[e];
    }
}

// ---------------- weight f32 -> bf16 conversion (once per call) ----------------

struct CvtArgs { const float* s[9]; ushort_t* d[9]; int n[9]; };

__global__ void k_cvt(CvtArgs a){
    int m = blockIdx.y;
    int i = (blockIdx.x * 256 + threadIdx.x) * 8;
    if (i < a.n[m]){
        const float* sp = a.s[m] + i;
        float4 f0 = *(const float4*)sp;
        float4 f1 = *(const float4*)(sp + 4);
        uint4 u;
        u.x = (uint_t)f2b(f0.x) | ((uint_t)f2b(f0.y) << 16);
        u.y = (uint_t)f2b(f0.z) | ((uint_t)f2b(f0.w) << 16);
        u.z = (uint_t)f2b(f1.x) | ((uint_t)f2b(f1.y) << 16);
        u.w = (uint_t)f2b(f1.z) | ((uint_t)f2b(f1.w) << 16);
        *(uint4*)&a.d[m][i] = u;
    }
}

// ---------------- pe = w_pe^T + b_pe (LDS tile transpose, f32 -> bf16) ----------------

__global__ void k_pe(const float* __restrict__ w_pe, const float* __restrict__ b_pe,
                     ushort_t* __restrict__ h0){
    __shared__ float lt[64][68];  // [n_local][i_local], padded
    int t = threadIdx.x;
    int n0 = blockIdx.x * 64, i0 = blockIdx.y * 64;
    int nc = (t & 15) * 4, ir = t >> 4;   // ir 0..15
    #pragma unroll
    for (int p = 0; p < 4; ++p){
        int i_loc = ir + p * 16;
        float4 v = {0.f, 0.f, 0.f, 0.f};
        if (n0 + nc < N_NODES)
            v = *(const float4*)&w_pe[(size_t)(i0 + i_loc) * N_NODES + n0 + nc];
        lt[nc + 0][i_loc] = v.x;
        lt[nc + 1][i_loc] = v.y;
        lt[nc + 2][i_loc] = v.z;
        lt[nc + 3][i_loc] = v.w;
    }
    __syncthreads();
    int ic = t & 7, nr = t >> 3;   // nr 0..31
    #pragma unroll
    for (int p = 0; p < 2; ++p){
        int n_loc = nr + p * 32;
        int n = n0 + n_loc;
        if (n < N_NODES){
            uint4 u;
            uint_t w01 = (uint_t)f2b(lt[n_loc][ic*8+0] + b_pe[i0+ic*8+0])
                       | ((uint_t)f2b(lt[n_loc][ic*8+1] + b_pe[i0+ic*8+1]) << 16);
            uint_t w23 = (uint_t)f2b(lt[n_loc][ic*8+2] + b_pe[i0+ic*8+2])
                       | ((uint_t)f2b(lt[n_loc][ic*8+3] + b_pe[i0+ic*8+3]) << 16);
            uint_t w45 = (uint_t)f2b(lt[n_loc][ic*8+4] + b_pe[i0+ic*8+4])
                       | ((uint_t)f2b(lt[n_loc][ic*8+5] + b_pe[i0+ic*8+5]) << 16);
            uint_t w67 = (uint_t)f2b(lt[n_loc][ic*8+6] + b_pe[i0+ic*8+6])
                       | ((uint_t)f2b(lt[n_loc][ic*8+7] + b_pe[i0+ic*8+7]) << 16);
            u.x = w01; u.y = w23; u.z = w45; u.w = w67;
            *(uint4*)&h0[(size_t)n * DIN + i0 + ic * 8] = u;
        }
    }
}

// ---------------- mean aggregation v2: panel-split + deep MLP + 4 indep chains ----
// grid (2500, 4): blockIdx.y = 128-dim panel (2.56MB < 4MB per-XCD L2).
// wave = one node; lane covers 2 dims (4B). 8 loads in flight, 4 indep acc pairs.

__global__ __launch_bounds__(256) void k_agg(
    const ushort_t* __restrict__ X, const int* __restrict__ row_ptr,
    const int* __restrict__ srcs, ushort_t* __restrict__ out)
{
    int w = threadIdx.x >> 6, lane = threadIdx.x & 63;
    int n = blockIdx.x * 4 + w;
    int col = blockIdx.y * 128 + lane * 2;
    int beg = row_ptr[n], end = row_ptr[n + 1];
    const ushort_t* Xc = X + col;
    float a0=0.f,a1=0.f, p0=0.f,p1=0.f, c0=0.f,c1=0.f, d0=0.f,d1=0.f;
    int j = beg;
    for (; j + 8 <= end; j += 8){
        int s0=srcs[j+0], s1=srcs[j+1], s2=srcs[j+2], s3=srcs[j+3];
        int s4=srcs[j+4], s5=srcs[j+5], s6=srcs[j+6], s7=srcs[j+7];
        uint_t v0 = *(const uint_t*)&Xc[(size_t)s0 * 512];
        uint_t v1 = *(const uint_t*)&Xc[(size_t)s1 * 512];
        uint_t v2 = *(const uint_t*)&Xc[(size_t)s2 * 512];
        uint_t v3 = *(const uint_t*)&Xc[(size_t)s3 * 512];
        uint_t v4 = *(const uint_t*)&Xc[(size_t)s4 * 512];
        uint_t v5 = *(const uint_t*)&Xc[(size_t)s5 * 512];
        uint_t v6 = *(const uint_t*)&Xc[(size_t)s6 * 512];
        uint_t v7 = *(const uint_t*)&Xc[(size_t)s7 * 512];
        a0 += blo(v0); a1 += bhi(v0);
        p0 += blo(v1); p1 += bhi(v1);
        c0 += blo(v2); c1 += bhi(v2);
        d0 += blo(v3); d1 += bhi(v3);
        a0 += blo(v4); a1 += bhi(v4);
        p0 += blo(v5); p1 += bhi(v5);
        c0 += blo(v6); c1 += bhi(v6);
        d0 += blo(v7); d1 += bhi(v7);
    }
    for (; j + 2 <= end; j += 2){
        int s0 = srcs[j], s1 = srcs[j + 1];
        uint_t v0 = *(const uint_t*)&Xc[(size_t)s0 * 512];
        uint_t v1 = *(const uint_t*)&Xc[(size_t)s1 * 512];
        a0 += blo(v0); a1 += bhi(v0);
        p0 += blo(v1); p1 += bhi(v1);
    }
    if (j < end){
        int s = srcs[j];
        uint_t v = *(const uint_t*)&Xc[(size_t)s * 512];
        c0 += blo(v); c1 += bhi(v);
    }
    float s0f = (a0 + p0) + (c0 + d0);
    float s1f = (a1 + p1) + (c1 + d1);
    float inv = (end > beg) ? 1.f / (float)(end - beg) : 1.f;
    uint_t o = (uint_t)f2b(s0f * inv) | ((uint_t)f2b(s1f * inv) << 16);
    *(uint_t*)&out[(size_t)n * 512 + col] = o;
}

// ---------------- fused SAGE layer: one-batch BM=160 geometry ----------------
// BM=160, BN=64, BK=32; 4 waves (2x2), wave tile 80x64 (5x2 MFMA blocks);
// LDS 64KB double-buffered -> exactly 2 blocks/CU; one co-resident batch.
// Blocks sharing an m-tile land on the same XCD (bid%8 = m%8).
// Y(f32) = [leaky?](X@Ws^T + Agg@Wn^T + b) + X@Wr^T + rb

template<int DO, bool ACT, bool DUAL2, bool WRITE_BF>
__global__ __launch_bounds__(256, 2) void k_layer(
    const ushort_t* __restrict__ X, const ushort_t* __restrict__ G,
    const ushort_t* __restrict__ Ws, const ushort_t* __restrict__ Wn,
    const ushort_t* __restrict__ Wr,
    const float* __restrict__ b, const float* __restrict__ rb,
    float* __restrict__ Y, float* __restrict__ Y2, ushort_t* __restrict__ YB)
{
    // per 32KB buffer (ushort offsets): X:[0,5120) G:[5120,10240) Ws:[10240,12288)
    // Wn:[12288,14336) Wr:[14336,16384)  — rows of 32 elems (64B), linear for gll16
    __shared__ __align__(16) ushort_t smem[2][16384];

    int t = threadIdx.x;
    constexpr int NT = DO / 64;
    int bid = blockIdx.x;
    int r8 = bid & 7, q = bid >> 3;
    int m_t = (q / NT) * 8 + r8;
    int n_t = q % NT;
    if (m_t * 160 >= N_NODES) return;   // uniform whole-block guard
    int m0 = m_t * 160, n0 = n_t * 64;

    int lane = t & 63, w = t >> 6;
    int wr = w >> 1, wc = w & 1;        // wave tile: rows wr*80, cols wc*32

    // staging: 32 chunks of 1KB (16 rows x 64B), 8 per wave
    const ushort_t* gptr[8];
    int coff[8];
    int rl = lane >> 2, sl = (lane & 3) * 8;
    #pragma unroll
    for (int i = 0; i < 8; ++i){
        int qq = w * 8 + i;
        const ushort_t* gA; int rowbase, off;
        if (qq < 10)      { gA = X;  rowbase = m0 + qq * 16;        off = qq * 512; }
        else if (qq < 20) { gA = G;  rowbase = m0 + (qq - 10) * 16; off = 5120 + (qq - 10) * 512; }
        else if (qq < 24) { gA = Ws; rowbase = n0 + (qq - 20) * 16; off = 10240 + (qq - 20) * 512; }
        else if (qq < 28) { gA = Wn; rowbase = n0 + (qq - 24) * 16; off = 12288 + (qq - 24) * 512; }
        else              { gA = Wr; rowbase = n0 + (qq - 28) * 16; off = 14336 + (qq - 28) * 512; }
        gptr[i] = gA + (size_t)(rowbase + rl) * 512 + sl;
        coff[i] = off;   // wave-uniform; HW writes base + lane*16B
    }

    f32x4 accS[5][2] = {}, accG[5][2] = {}, accR[5][2] = {};
    int arow = wr * 80 + (lane & 15);
    int brow = wc * 32 + (lane & 15);
    int kk = (lane >> 4) * 8;

    // prologue: stage K-step 0 into buffer 0
    #pragma unroll
    for (int i = 0; i < 8; ++i) gll16(gptr[i], &smem[0][coff[i]]);
    __syncthreads();

    int cur = 0;
    for (int ks = 0; ks < 16; ++ks){
        if (ks < 15){
            int k0 = (ks + 1) * 32;
            #pragma unroll
            for (int i = 0; i < 8; ++i) gll16(gptr[i] + k0, &smem[cur ^ 1][coff[i]]);
        }

        const ushort_t* sb = smem[cur];
        bf16x8 ax[5], ag[5], bs[2], bn_[2], brr[2];
        #pragma unroll
        for (int m = 0; m < 5; ++m){
            ax[m] = *(const bf16x8*)&sb[(arow + m * 16) * 32 + kk];
            ag[m] = *(const bf16x8*)&sb[5120 + (arow + m * 16) * 32 + kk];
        }
        #pragma unroll
        for (int n = 0; n < 2; ++n){
            bs[n]  = *(const bf16x8*)&sb[10240 + (brow + n * 16) * 32 + kk];
            bn_[n] = *(const bf16x8*)&sb[12288 + (brow + n * 16) * 32 + kk];
            brr[n] = *(const bf16x8*)&sb[14336 + (brow + n * 16) * 32 + kk];
        }
        #pragma unroll
        for (int m = 0; m < 5; ++m)
            #pragma unroll
            for (int n = 0; n < 2; ++n){
                accS[m][n] = __builtin_amdgcn_mfma_f32_16x16x32_bf16(ax[m], bs[n],  accS[m][n], 0, 0, 0);
                accG[m][n] = __builtin_amdgcn_mfma_f32_16x16x32_bf16(ag[m], bn_[n], accG[m][n], 0, 0, 0);
                accR[m][n] = __builtin_amdgcn_mfma_f32_16x16x32_bf16(ax[m], brr[n], accR[m][n], 0, 0, 0);
            }

        __syncthreads();   // next buffer staged; all waves done reading cur
        cur ^= 1;
    }

    // epilogue: C/D layout col = lane&15, row = (lane>>4)*4 + reg
    int col_l = lane & 15;
    int row_l = (lane >> 4) * 4;
    #pragma unroll
    for (int n = 0; n < 2; ++n){
        int col = n0 + wc * 32 + n * 16 + col_l;
        float bb = b[col], rbb = rb[col];
        #pragma unroll
        for (int m = 0; m < 5; ++m){
            #pragma unroll
            for (int j = 0; j < 4; ++j){
                int row = m0 + wr * 80 + m * 16 + row_l + j;
                if (row < N_NODES){
                    float v = accS[m][n][j] + accG[m][n][j] + bb;
                    if (ACT) v = (v > 0.f) ? v : 0.01f * v;
                    v += accR[m][n][j] + rbb;
                    Y[(size_t)row * DO + col] = v;
                    if (DUAL2) Y2[(size_t)row * DO + col] = v;
                    if (WRITE_BF) YB[(size_t)row * DO + col] = f2b(v);
                }
            }
        }
    }
}

// ---------------- launch ----------------

extern "C" void kernel_launch(void* const* d_in, const int* in_sizes, int n_in,
                              void* d_out, int out_size, void* d_ws, size_t ws_size,
                              hipStream_t stream) {
    const int* edge  = (const int*)d_in[0];
    const int* e_src = edge;
    const int* e_dst = edge + N_EDGES;
    const float* w_pe = (const float*)d_in[1];
    const float* b_pe = (const float*)d_in[2];
    const float* ws0 = (const float*)d_in[3];
    const float* wn0 = (const float*)d_in[4];
    const float* b0  = (const float*)d_in[5];
    const float* wr0 = (const float*)d_in[6];
    const float* rb0 = (const float*)d_in[7];
    const float* ws1 = (const float*)d_in[8];
    const float* wn1 = (const float*)d_in[9];
    const float* b1  = (const float*)d_in[10];
    const float* wr1 = (const float*)d_in[11];
    const float* rb1 = (const float*)d_in[12];
    const float* ws2 = (const float*)d_in[13];
    const float* wn2 = (const float*)d_in[14];
    const float* b2  = (const float*)d_in[15];
    const float* wr2 = (const float*)d_in[16];
    const float* rb2 = (const float*)d_in[17];

    char* wsb = (char*)d_ws;
    ushort_t* h0   = (ushort_t*)wsb;                       // 10,240,000 B
    ushort_t* hb   = (ushort_t*)(wsb + 10240000);          // 10,240,000 B
    ushort_t* aggb = (ushort_t*)(wsb + 20480000);          // 10,240,000 B
    ushort_t* wbf  = (ushort_t*)(wsb + 30720000);          // 3,932,160 B
    int* deg     = (int*)(wsb + 34652160);                 // 10016 ints
    int* row_ptr = deg + 10016;
    int* cursor  = row_ptr + 10016;
    int* srcs    = cursor + 10016;                         // 320000 ints

    ushort_t* wbf0s = wbf;
    ushort_t* wbf0n = wbf + 262144;
    ushort_t* wbf0r = wbf + 524288;
    ushort_t* wbf1s = wbf + 786432;
    ushort_t* wbf1n = wbf + 1048576;
    ushort_t* wbf1r = wbf + 1310720;
    ushort_t* wbf2s = wbf + 1572864;
    ushort_t* wbf2n = wbf + 1703936;
    ushort_t* wbf2r = wbf + 1835008;

    float* out  = (float*)d_out;
    float* fin  = out;               // [10000][256]
    float* mid0 = out + 2560000;     // [10000][512]
    float* mid1 = out + 7680000;     // [10000][512]
    float* mid2 = out + 12800000;    // [10000][256]

    k_zero   <<<40, 256, 0, stream>>>(deg);
    k_degree <<<1250, 256, 0, stream>>>(e_dst, deg);
    k_scan   <<<1, 256, 0, stream>>>(deg, row_ptr, cursor);
    k_scatter<<<1250, 256, 0, stream>>>(e_src, e_dst, cursor, srcs);

    CvtArgs ca;
    ca.s[0]=ws0; ca.s[1]=wn0; ca.s[2]=wr0;
    ca.s[3]=ws1; ca.s[4]=wn1; ca.s[5]=wr1;
    ca.s[6]=ws2; ca.s[7]=wn2; ca.s[8]=wr2;
    ca.d[0]=wbf0s; ca.d[1]=wbf0n; ca.d[2]=wbf0r;
    ca.d[3]=wbf1s; ca.d[4]=wbf1n; ca.d[5]=wbf1r;
    ca.d[6]=wbf2s; ca.d[7]=wbf2n; ca.d[8]=wbf2r;
    for (int i = 0; i < 6; ++i) ca.n[i] = 262144;
    for (int i = 6; i < 9; ++i) ca.n[i] = 131072;
    k_cvt<<<dim3(128, 9), 256, 0, stream>>>(ca);

    k_pe<<<dim3(157, 8), 256, 0, stream>>>(w_pe, b_pe, h0);

    // grid: 8 xcd-residues * NT n-tiles * 8 m-groups (BM=160: 63 m-tiles + guard)
    k_agg<<<dim3(2500, 4), 256, 0, stream>>>(h0, row_ptr, srcs, aggb);
    k_layer<512, true,  false, true ><<<dim3(512), 256, 0, stream>>>(
        h0, aggb, wbf0s, wbf0n, wbf0r, b0, rb0, mid0, nullptr, hb);

    k_agg<<<dim3(2500, 4), 256, 0, stream>>>(hb, row_ptr, srcs, aggb);
    k_layer<512, true,  false, true ><<<dim3(512), 256, 0, stream>>>(
        hb, aggb, wbf1s, wbf1n, wbf1r, b1, rb1, mid1, nullptr, h0);

    k_agg<<<dim3(2500, 4), 256, 0, stream>>>(h0, row_ptr, srcs, aggb);
    k_layer<256, false, true,  false><<<dim3(256), 256, 0, stream>>>(
        h0, aggb, wbf2s, wbf2n, wbf2r, b2, rb2, mid2, fin, nullptr);
}